// Round 12
// baseline (137.054 us; speedup 1.0000x reference)
//
#include <hip/hip_runtime.h>
#include <hip/hip_bf16.h>
#include <math.h>

namespace {

typedef __attribute__((ext_vector_type(8))) short    short8;
typedef __attribute__((ext_vector_type(4))) float    float4v;
typedef __attribute__((ext_vector_type(4))) unsigned uint4v;

constexpr float PI_F     = 3.14159265358979323846f;
constexpr float TWO_PI_F = 6.28318530717958647692f;

__device__ __forceinline__ unsigned pack2(float a, float b) {
    __hip_bfloat162 h = __float22bfloat162_rn(float2{a, b});
    unsigned r;
    __builtin_memcpy(&r, &h, 4);
    return r;
}

union Frag { unsigned u[4]; short8 s; };

__device__ __forceinline__ void gl2lds16(const void* g, void* l) {
    __builtin_amdgcn_global_load_lds(
        (const __attribute__((address_space(1))) void*)g,
        (__attribute__((address_space(3))) void*)l, 16, 0, 0);
}

// trig -> 4 B-frags (ks0=cos lo, ks1=cos hi, ks2=sin lo, ks3=sin hi).
// No fract: v_sin/v_cos take revolutions, handle |x| <= 256 internally.
__device__ __forceinline__ void make_xf(const float* __restrict__ fq,
                                        float fe, int g, Frag* xf) {
    float cl[8], sl[8], ch8[8], sh8[8];
    #pragma unroll
    for (int j = 0; j < 8; ++j) {
        const float tL = fe * fq[8 * g + j];
        const float tH = fe * fq[32 + 8 * g + j];
        sl[j]  = __builtin_amdgcn_sinf(tL);
        cl[j]  = __builtin_amdgcn_cosf(tL);
        sh8[j] = __builtin_amdgcn_sinf(tH);
        ch8[j] = __builtin_amdgcn_cosf(tH);
    }
    #pragma unroll
    for (int p = 0; p < 4; ++p) {
        xf[0].u[p] = pack2(cl[2 * p],  cl[2 * p + 1]);
        xf[1].u[p] = pack2(ch8[2 * p], ch8[2 * p + 1]);
        xf[2].u[p] = pack2(sl[2 * p],  sl[2 * p + 1]);
        xf[3].u[p] = pack2(sh8[2 * p], sh8[2 * p + 1]);
    }
}

// ---- prep: transpose + bf16 weights.
// W1T[d][n][k]   = W1[d][k][n]               (k < 128; k=128 handled as f32 rank-1)
// W2T[d][n][ks_] = W2[d][pi(ks_)][n], pi makes GEMM2's B-frag lane-local:
//   pi(kslot) = 32*(kslot>>5) + 16*((kslot>>2)&1) + 4*((kslot>>3)&3) + (kslot&3)
__global__ __launch_bounds__(256)
void prep_weights(const float* __restrict__ W1,
                  const float* __restrict__ W2,
                  ushort* __restrict__ W1T,
                  ushort* __restrict__ W2T) {
    const int idx = blockIdx.x * 256 + threadIdx.x;   // 0 .. 131071
    if (idx < 65536) {
        const int d = idx >> 14;
        const int n = (idx >> 7) & 127;
        const int k = idx & 127;
        __hip_bfloat16 v = __float2bfloat16(W1[(d * 129 + k) * 128 + n]);
        ushort u; __builtin_memcpy(&u, &v, 2);
        W1T[idx] = u;
    } else {
        const int j = idx - 65536;
        const int d = j >> 14;
        const int n = (j >> 7) & 127;
        const int kslot = j & 127;
        const int c = 32 * (kslot >> 5) + 16 * ((kslot >> 2) & 1)
                    + 4 * ((kslot >> 3) & 3) + (kslot & 3);
        __hip_bfloat16 v = __float2bfloat16(W2[(d * 128 + c) * 128 + n]);
        ushort u; __builtin_memcpy(&u, &v, 2);
        W2T[j] = u;
    }
}

// stage one 16KB half-tile (16 x 1KB chunks) with 4 waves: wave wv stages
// chunks 4wv..4wv+3. chunk c = tt*4+ks holds A-frags for t = 4*half+tt, kstep ks.
__device__ __forceinline__ void stage_half(const ushort* __restrict__ Wtile,
                                           int half, ushort* slot, int wv, int lane) {
    const int e4 = lane & 15;
    const int g  = lane >> 4;
    #pragma unroll
    for (int i = 0; i < 4; ++i) {
        const int c  = 4 * wv + i;
        const int tt = c >> 2;
        const int ks = c & 3;
        const ushort* gp = Wtile + (16 * (4 * half + tt) + e4) * 128 + g * 8 + 32 * ks;
        gl2lds16(gp, slot + c * 512);
    }
}

// ---- main fused kernel ----
// 4 waves x 16 edges = 64 edges/block; 4 independent blocks/CU (LDS = 40960B).
// Transposed math: h^T = W1^T x^T. 16x16x32 MFMA.
// A (weights): row = lane&15 (ch%16), kslot = (lane>>4)*8+j+32ks.
// B (x / h): col = lane&15 (edge), same kslot layout.
// C: col = lane&15 (edge), ch = 16t + 4*(lane>>4) + reg.
// 4 phases/d; 2 ping-pong 16KB slots; each phase stages the NEXT phase's
// half into the slot freed by the previous phase; plain __syncthreads.
__global__ __launch_bounds__(256, 4)
void rcpe_q(const float* __restrict__ source,
            const float* __restrict__ target,
            const int*   __restrict__ edge,
            const float* __restrict__ freqs,
            const float* __restrict__ W1,      // f32, for k=128 rank-1 row
            const ushort* __restrict__ W1T,
            const float* __restrict__ b1,
            const float* __restrict__ gamma,
            const float* __restrict__ beta,
            const ushort* __restrict__ W2T,
            const float* __restrict__ b2,
            float* __restrict__ out,
            int E)
{
    __shared__ __align__(16) ushort wbuf[2][8192];     // 2 x 16 KB ping-pong
    __shared__ __align__(16) float b1_lds[4][128];     // 2 KB
    __shared__ __align__(16) float w1r_lds[4][128];    // 2 KB
    __shared__ __align__(16) unsigned gmbt_lds[4][128];// 2 KB (bf16 gamma|beta)
    __shared__ __align__(16) float feat_lds[4][64];    // 1 KB
    __shared__ __align__(16) float freq_lds[4][64];    // 1 KB

    const int tid  = threadIdx.x;     // 0..255
    const int wv   = tid >> 6;        // 0..3
    const int lane = tid & 63;
    const int e4   = lane & 15;
    const int g    = lane >> 4;       // 0..3
    const int ebase = blockIdx.x * 64;
    const int eg    = ebase + wv * 16 + e4;

    // ---- prologue: stage W1[0]h0 -> slot0, then tables ----
    stage_half(W1T, 0, wbuf[0], wv, lane);

    #pragma unroll
    for (int i = 0; i < 2; ++i) {     // 512-elem tables, 256 threads
        const int idx = tid + 256 * i;
        const int dd = idx >> 7, c = idx & 127;
        b1_lds[dd][c]   = b1[idx];
        w1r_lds[dd][c]  = W1[(dd * 129 + 128) * 128 + c];
        gmbt_lds[dd][c] = pack2(gamma[idx], beta[idx]);
    }
    ((float*)freq_lds)[tid] = freqs[tid];   // freqs is [4][64] = 256

    if (tid < 64) {   // features: 64 edges/block; E = 3125*64 exact
        const int e   = ebase + tid;
        const int s_i = edge[e];
        const int t_i = edge[E + e];
        const float sx = source[s_i * 3 + 0];
        const float sy = source[s_i * 3 + 1];
        const float sh = source[s_i * 3 + 2];
        const float tx = target[t_i * 5 + 0];
        const float ty = target[t_i * 5 + 1];
        const float th = target[t_i * 5 + 2];
        const float ts = target[t_i * 5 + 3];
        const float dx = sx - tx;
        const float dy = sy - ty;
        float a = sh - th + PI_F;
        a = fmodf(a, TWO_PI_F);
        if (a < 0.0f) a += TWO_PI_F;
        const float dh  = a - PI_F;
        const float ang = atan2f(dy, dx);
        const float tvx = ts * cosf(th);
        const float tvy = ts * sinf(th);
        const float closing = tvx * cosf(ang) + tvy * sinf(ang);
        feat_lds[0][tid] = dx;
        feat_lds[1][tid] = dy;
        feat_lds[2][tid] = dh;
        feat_lds[3][tid] = closing;
    }

    // y init: sum_d b2 (C layout: ch = 16t + 4g + r)
    float4v y[8];
    #pragma unroll
    for (int t = 0; t < 8; ++t) {
        float4v a = {0.f, 0.f, 0.f, 0.f};
        #pragma unroll
        for (int d = 0; d < 4; ++d) {
            const float4v bv = *(const float4v*)(b2 + d * 128 + 16 * t + 4 * g);
            #pragma unroll
            for (int r = 0; r < 4; ++r) a[r] += bv[r];
        }
        y[t] = a;
    }

    __syncthreads();   // slot0 landed; tables ready

    // d=0 trig in prologue (subsequent d's computed in P3 of previous d)
    float fe = feat_lds[0][wv * 16 + e4];
    Frag xf[4];
    make_xf(freq_lds[0], fe, g, xf);

    ushort* sA = wbuf[0];   // current phase's slot
    ushort* sB = wbuf[1];   // staging target (freed by previous phase)
    #define SWAP() { ushort* _t = sA; sA = sB; sB = _t; }

    #pragma unroll 1
    for (int d = 0; d < 4; ++d) {
        // ===== P0: stage W1[d]h1 -> sB ; GEMM1 t0-3 from sA (init fuses rank-1) ====
        stage_half(W1T + d * 16384, 1, sB, wv, lane);

        float4v hacc[8];
        __builtin_amdgcn_s_setprio(1);
        #pragma unroll
        for (int t = 0; t < 4; ++t) {
            const float4v bv  = *(const float4v*)&b1_lds[d][16 * t + 4 * g];
            const float4v wr4 = *(const float4v*)&w1r_lds[d][16 * t + 4 * g];
            float4v acc;
            #pragma unroll
            for (int r = 0; r < 4; ++r) acc[r] = fmaf(fe, wr4[r], bv[r]);
            #pragma unroll
            for (int ks = 0; ks < 4; ++ks) {
                const short8 aw = *(const short8*)&sA[(t * 4 + ks) * 512 + lane * 8];
                acc = __builtin_amdgcn_mfma_f32_16x16x32_bf16(aw, xf[ks].s, acc, 0, 0, 0);
            }
            hacc[t] = acc;
        }
        __builtin_amdgcn_s_setprio(0);
        __syncthreads();
        SWAP();

        // ===== P1: stage W2[d]h0 -> sB ; GEMM1 t4-7 from sA =====
        stage_half(W2T + d * 16384, 0, sB, wv, lane);

        __builtin_amdgcn_s_setprio(1);
        #pragma unroll
        for (int t = 4; t < 8; ++t) {
            const float4v bv  = *(const float4v*)&b1_lds[d][16 * t + 4 * g];
            const float4v wr4 = *(const float4v*)&w1r_lds[d][16 * t + 4 * g];
            float4v acc;
            #pragma unroll
            for (int r = 0; r < 4; ++r) acc[r] = fmaf(fe, wr4[r], bv[r]);
            #pragma unroll
            for (int ks = 0; ks < 4; ++ks) {
                const short8 aw = *(const short8*)&sA[((t - 4) * 4 + ks) * 512 + lane * 8];
                acc = __builtin_amdgcn_mfma_f32_16x16x32_bf16(aw, xf[ks].s, acc, 0, 0, 0);
            }
            hacc[t] = acc;
        }
        __builtin_amdgcn_s_setprio(0);
        __syncthreads();
        SWAP();

        // ===== P2: stage W2[d]h1 -> sB ; LN ; pack ; GEMM2 t0-3 from sA =====
        stage_half(W2T + d * 16384, 1, sB, wv, lane);

        float sm = 0.f, sq = 0.f;
        #pragma unroll
        for (int t = 0; t < 8; ++t) {
            #pragma unroll
            for (int r = 0; r < 4; ++r) {
                const float v = hacc[t][r];
                sm += v;
                sq = fmaf(v, v, sq);
            }
        }
        sm += __shfl_xor(sm, 16, 64);
        sq += __shfl_xor(sq, 16, 64);
        sm += __shfl_xor(sm, 32, 64);
        sq += __shfl_xor(sq, 32, 64);
        const float mu   = sm * (1.f / 128.f);
        const float var  = sq * (1.f / 128.f) - mu * mu;
        const float rinv = rsqrtf(var + 1e-5f);
        #pragma unroll
        for (int t = 0; t < 8; ++t) {
            const uint4v gb = *(const uint4v*)&gmbt_lds[d][16 * t + 4 * g];
            #pragma unroll
            for (int r = 0; r < 4; ++r) {
                const float gv = __uint_as_float(gb[r] << 16);
                const float bv = __uint_as_float(gb[r] & 0xFFFF0000u);
                float v = (hacc[t][r] - mu) * rinv;
                v = fmaf(v, gv, bv);
                hacc[t][r] = fmaxf(v, 0.f);
            }
        }

        Frag bfr[4];   // zero-shuffle B-frags (pi-permuted W2T makes them lane-local)
        #pragma unroll
        for (int ks = 0; ks < 4; ++ks) {
            bfr[ks].u[0] = pack2(hacc[2 * ks][0],     hacc[2 * ks][1]);
            bfr[ks].u[1] = pack2(hacc[2 * ks][2],     hacc[2 * ks][3]);
            bfr[ks].u[2] = pack2(hacc[2 * ks + 1][0], hacc[2 * ks + 1][1]);
            bfr[ks].u[3] = pack2(hacc[2 * ks + 1][2], hacc[2 * ks + 1][3]);
        }

        __builtin_amdgcn_s_setprio(1);
        #pragma unroll
        for (int t = 0; t < 4; ++t) {
            float4v acc = y[t];
            #pragma unroll
            for (int ks = 0; ks < 4; ++ks) {
                const short8 aw = *(const short8*)&sA[(t * 4 + ks) * 512 + lane * 8];
                acc = __builtin_amdgcn_mfma_f32_16x16x32_bf16(aw, bfr[ks].s, acc, 0, 0, 0);
            }
            y[t] = acc;
        }
        __builtin_amdgcn_s_setprio(0);
        __syncthreads();
        SWAP();

        // ===== P3: stage W1[d+1]h0 -> sB ; GEMM2 t4-7 from sA ; trig for d+1 ====
        if (d < 3) stage_half(W1T + (d + 1) * 16384, 0, sB, wv, lane);

        __builtin_amdgcn_s_setprio(1);
        #pragma unroll
        for (int t = 4; t < 8; ++t) {
            float4v acc = y[t];
            #pragma unroll
            for (int ks = 0; ks < 4; ++ks) {
                const short8 aw = *(const short8*)&sA[((t - 4) * 4 + ks) * 512 + lane * 8];
                acc = __builtin_amdgcn_mfma_f32_16x16x32_bf16(aw, bfr[ks].s, acc, 0, 0, 0);
            }
            y[t] = acc;
        }
        __builtin_amdgcn_s_setprio(0);

        if (d < 3) {   // trig for next d overlaps GEMM2's MFMA/LDS shadow
            fe = feat_lds[d + 1][wv * 16 + e4];
            make_xf(freq_lds[d + 1], fe, g, xf);
            __syncthreads();
        }
        SWAP();
    }
    #undef SWAP

    // ---- store: 4 g-lanes per edge form full 64B sectors ----
    #pragma unroll
    for (int t = 0; t < 8; ++t) {
        *(float4v*)(out + eg * 128 + 16 * t + 4 * g) = y[t];
    }
}

} // namespace

extern "C" void kernel_launch(void* const* d_in, const int* in_sizes, int n_in,
                              void* d_out, int out_size, void* d_ws, size_t ws_size,
                              hipStream_t stream) {
    const float* source = (const float*)d_in[0];
    const float* target = (const float*)d_in[1];
    const int*   edge   = (const int*)  d_in[2];
    const float* freqs  = (const float*)d_in[3];
    const float* W1     = (const float*)d_in[4];
    const float* b1     = (const float*)d_in[5];
    const float* gammap = (const float*)d_in[6];
    const float* betap  = (const float*)d_in[7];
    const float* W2     = (const float*)d_in[8];
    const float* b2     = (const float*)d_in[9];
    float* out = (float*)d_out;

    ushort* W1T = (ushort*)d_ws;                       // 131072 B
    ushort* W2T = (ushort*)((char*)d_ws + 131072);     // 131072 B

    const int E = in_sizes[2] / 2;      // edge is (2, E); E = 200000

    prep_weights<<<dim3(512), dim3(256), 0, stream>>>(W1, W2, W1T, W2T);

    const int nblocks = E / 64;         // 3125, exact
    rcpe_q<<<dim3(nblocks), dim3(256), 0, stream>>>(
        source, target, edge, freqs, W1, W1T, b1, gammap, betap, W2T, b2, out, E);
}

// Round 13
// 116.502 us; speedup vs baseline: 1.1764x; 1.1764x over previous
//
#include <hip/hip_runtime.h>
#include <hip/hip_bf16.h>
#include <math.h>

namespace {

typedef __attribute__((ext_vector_type(8)))  short    short8;
typedef __attribute__((ext_vector_type(4)))  float    float4v;
typedef __attribute__((ext_vector_type(16))) float    f32x16;
typedef __attribute__((ext_vector_type(4)))  unsigned uint4v;

constexpr float PI_F     = 3.14159265358979323846f;
constexpr float TWO_PI_F = 6.28318530717958647692f;

__device__ __forceinline__ unsigned pack2(float a, float b) {
    __hip_bfloat162 h = __float22bfloat162_rn(float2{a, b});
    unsigned r;
    __builtin_memcpy(&r, &h, 4);
    return r;
}

union Frag { unsigned u[4]; short8 s; };

__device__ __forceinline__ void gl2lds16(const void* g, void* l) {
    __builtin_amdgcn_global_load_lds(
        (const __attribute__((address_space(1))) void*)g,
        (__attribute__((address_space(3))) void*)l, 16, 0, 0);
}

// counted phase barrier: vmcnt(4) leaves THIS phase's 4 stage-loads in flight,
// forces the previous phase's stage landed (r9-proven ledger, 4-chunk stages).
__device__ __forceinline__ void pb4() {
    asm volatile("s_waitcnt vmcnt(4) lgkmcnt(0)" ::: "memory");
    __builtin_amdgcn_s_barrier();
    __builtin_amdgcn_sched_barrier(0);
}
__device__ __forceinline__ void pb0() {
    asm volatile("s_waitcnt vmcnt(0) lgkmcnt(0)" ::: "memory");
    __builtin_amdgcn_s_barrier();
    __builtin_amdgcn_sched_barrier(0);
}

// ---- prep: weights in frag-linear chunk order for 32x32x16 MFMA ----
// Chunk c = tau*8 + K (tau = ch-tile 0..3, K = kstep 0..7), 1KB each.
// W1T chunk value at (lane l, elem j): W1[d][k][ch], ch = 32*tau + (l&31),
//   k = 16*K + 8*(l>>5) + j.       (k=128 raw-feature handled as f32 rank-1)
// W2T applies pi so GEMM2's B-frag is lane-local:
//   reg = 8*(K&1)+j; ch_h = 32*(K>>1) + (reg&3) + 8*(reg>>2) + 4*(l>>5);
//   value = W2[d][ch_h][ch'], ch' = 32*tau + (l&31).
__global__ __launch_bounds__(256)
void prep_weights(const float* __restrict__ W1,
                  const float* __restrict__ W2,
                  ushort* __restrict__ W1T,
                  ushort* __restrict__ W2T) {
    const int idx = blockIdx.x * 256 + threadIdx.x;   // 0 .. 131071
    const int r   = idx & 0xFFFF;
    const int d   = r >> 14;
    const int rem = r & 16383;
    const int c   = rem >> 9;
    const int l   = (rem >> 3) & 63;
    const int j   = rem & 7;
    const int tau = c >> 3;
    const int K   = c & 7;
    if (idx < 65536) {
        const int ch = 32 * tau + (l & 31);
        const int k  = 16 * K + 8 * (l >> 5) + j;
        __hip_bfloat16 v = __float2bfloat16(W1[(d * 129 + k) * 128 + ch]);
        ushort u; __builtin_memcpy(&u, &v, 2);
        W1T[r] = u;
    } else {
        const int reg  = 8 * (K & 1) + j;
        const int ch_h = 32 * (K >> 1) + (reg & 3) + 8 * (reg >> 2) + 4 * (l >> 5);
        const int chp  = 32 * tau + (l & 31);
        __hip_bfloat16 v = __float2bfloat16(W2[(d * 128 + ch_h) * 128 + chp]);
        ushort u; __builtin_memcpy(&u, &v, 2);
        W2T[r] = u;
    }
}

// stage one 16KB half-tile (16 x 1KB chunks) with 4 waves: wave wv stages
// chunks 4wv..4wv+3 of the half. Source is frag-linear, dest wave-uniform.
__device__ __forceinline__ void stage_half(const ushort* __restrict__ Wtile,
                                           int half, ushort* slot, int wv, int lane) {
    #pragma unroll
    for (int i = 0; i < 4; ++i) {
        const int cl = 4 * wv + i;             // chunk within half
        const int c  = 16 * half + cl;         // chunk within tile
        gl2lds16(Wtile + c * 512 + lane * 8, slot + cl * 512);
    }
}

// ---- main fused kernel: 32x32x16 MFMA, 32 edges/wave ----
// 4 waves x 32 edges = 128 edges/block. Transposed math: h^T = W1^T x^T.
// A (weights): row = lane&31, kslot = 8*(lane>>5)+j.   B (x/h): col = lane&31
// (edge), same kslot layout.  C: col = lane&31 (edge),
// ch = 32*tile + (reg&3) + 8*(reg>>2) + 4*(lane>>5)  [HW-verified r3].
// 4 phases/d; 3 rotating 16KB slots; stage issued 2 phases ahead (r9 ledger).
__global__ __launch_bounds__(256, 2)
void rcpe_w32(const float* __restrict__ source,
              const float* __restrict__ target,
              const int*   __restrict__ edge,
              const float* __restrict__ freqs,
              const float* __restrict__ W1,      // f32, for k=128 rank-1 row
              const ushort* __restrict__ W1T,
              const float* __restrict__ b1,
              const float* __restrict__ gamma,
              const float* __restrict__ beta,
              const ushort* __restrict__ W2T,
              const float* __restrict__ b2,
              float* __restrict__ out,
              int E)
{
    __shared__ __align__(16) ushort wbuf[3][8192];     // 3 x 16 KB rotating slots
    __shared__ __align__(16) float b1_lds[4][128];
    __shared__ __align__(16) float w1r_lds[4][128];
    __shared__ __align__(16) unsigned gmbt_lds[4][128];// bf16 gamma|beta packed
    __shared__ __align__(16) float feat_lds[4][128];
    __shared__ __align__(16) float freq_lds[4][64];

    const int tid  = threadIdx.x;     // 0..255
    const int wv   = tid >> 6;        // 0..3
    const int lane = tid & 63;
    const int e5   = lane & 31;       // edge within wave-tile (B col / C col)
    const int sh1  = lane >> 5;       // k-half / ch-offset lane split
    const int ebase = blockIdx.x * 128;
    const int eg    = ebase + wv * 32 + e5;

    // ---- prologue: issue phase-0/1 stages FIRST (oldest in vmem FIFO) ----
    stage_half(W1T, 0, wbuf[0], wv, lane);   // P0 data: W1[0] tau0,1
    stage_half(W1T, 1, wbuf[1], wv, lane);   // P1 data: W1[0] tau2,3
    __builtin_amdgcn_sched_barrier(0);       // pin stage issue before other vmem

    #pragma unroll
    for (int i = 0; i < 2; ++i) {     // param tables (prologue-only vmem)
        const int idx = tid + 256 * i;
        const int dd = idx >> 7, c = idx & 127;
        b1_lds[dd][c]   = b1[idx];
        w1r_lds[dd][c]  = W1[(dd * 129 + 128) * 128 + c];
        gmbt_lds[dd][c] = pack2(gamma[idx], beta[idx]);
    }
    ((float*)freq_lds)[tid] = freqs[tid];   // freqs is [4][64] = 256

    if (tid < 128) {
        const int e  = ebase + tid;
        const int ec = (e < E) ? e : (E - 1);
        const int s_i = edge[ec];
        const int t_i = edge[E + ec];
        const float sx = source[s_i * 3 + 0];
        const float sy = source[s_i * 3 + 1];
        const float sh = source[s_i * 3 + 2];
        const float tx = target[t_i * 5 + 0];
        const float ty = target[t_i * 5 + 1];
        const float th = target[t_i * 5 + 2];
        const float ts = target[t_i * 5 + 3];
        const float dx = sx - tx;
        const float dy = sy - ty;
        float a = sh - th + PI_F;
        a = fmodf(a, TWO_PI_F);
        if (a < 0.0f) a += TWO_PI_F;
        const float dh  = a - PI_F;
        const float ang = atan2f(dy, dx);
        const float tvx = ts * cosf(th);
        const float tvy = ts * sinf(th);
        const float closing = tvx * cosf(ang) + tvy * sinf(ang);
        feat_lds[0][tid] = dx;
        feat_lds[1][tid] = dy;
        feat_lds[2][tid] = dh;
        feat_lds[3][tid] = closing;
    }

    // y init: sum_d b2, C layout elem 4rq+rr -> ch = 32*tp + 8*rq + 4*sh1 + rr
    f32x16 y[4];
    #pragma unroll
    for (int tp = 0; tp < 4; ++tp) {
        #pragma unroll
        for (int rq = 0; rq < 4; ++rq) {
            float4v a = {0.f, 0.f, 0.f, 0.f};
            #pragma unroll
            for (int d = 0; d < 4; ++d) {
                const float4v bv = *(const float4v*)(b2 + d * 128 + 32 * tp + 8 * rq + 4 * sh1);
                #pragma unroll
                for (int rr = 0; rr < 4; ++rr) a[rr] += bv[rr];
            }
            #pragma unroll
            for (int rr = 0; rr < 4; ++rr) y[tp][4 * rq + rr] = a[rr];
        }
    }

    pb4();   // b2's compiler drain already forced slot0/1; ledger starts clean

    ushort* su  = wbuf[0];
    ushort* s1a = wbuf[1];
    ushort* s2a = wbuf[2];
    #define ROTATE() { ushort* _t = su; su = s1a; s1a = s2a; s2a = _t; }

    #pragma unroll 1
    for (int d = 0; d < 4; ++d) {
        // ===== P0: stage W2[d]h0 -> s2a ; trig ; GEMM1 tau0,1 from su =====
        stage_half(W2T + d * 16384, 0, s2a, wv, lane);

        const float fe = feat_lds[d][wv * 32 + e5];

        Frag xf[8];   // K=0..3 cos(k=16K+8sh1+j), K=4..7 sin (same freqs)
        #pragma unroll
        for (int K = 0; K < 4; ++K) {
            float cs[8], sn[8];
            #pragma unroll
            for (int j = 0; j < 8; ++j) {
                const float a = fe * freq_lds[d][16 * K + 8 * sh1 + j];
                sn[j] = __builtin_amdgcn_sinf(a);   // revolutions; |a| < ~60
                cs[j] = __builtin_amdgcn_cosf(a);
            }
            #pragma unroll
            for (int q = 0; q < 4; ++q) {
                xf[K].u[q]     = pack2(cs[2 * q], cs[2 * q + 1]);
                xf[K + 4].u[q] = pack2(sn[2 * q], sn[2 * q + 1]);
            }
        }

        f32x16 hacc[4];
        #pragma unroll
        for (int tp = 0; tp < 2; ++tp) {   // init (fuses f32 rank-1 + b1)
            #pragma unroll
            for (int rq = 0; rq < 4; ++rq) {
                const float4v bq = *(const float4v*)&b1_lds[d][32 * tp + 8 * rq + 4 * sh1];
                const float4v wq = *(const float4v*)&w1r_lds[d][32 * tp + 8 * rq + 4 * sh1];
                #pragma unroll
                for (int rr = 0; rr < 4; ++rr)
                    hacc[tp][4 * rq + rr] = fmaf(fe, wq[rr], bq[rr]);
            }
        }
        __builtin_amdgcn_s_setprio(1);
        #pragma unroll
        for (int K = 0; K < 8; ++K) {
            #pragma unroll
            for (int tp = 0; tp < 2; ++tp) {
                const short8 aw = *(const short8*)&su[(tp * 8 + K) * 512 + lane * 8];
                hacc[tp] = __builtin_amdgcn_mfma_f32_32x32x16_bf16(aw, xf[K].s, hacc[tp], 0, 0, 0);
            }
        }
        __builtin_amdgcn_s_setprio(0);
        pb4();
        ROTATE();

        // ===== P1: stage W2[d]h1 -> s2a ; GEMM1 tau2,3 from su =====
        stage_half(W2T + d * 16384, 1, s2a, wv, lane);

        #pragma unroll
        for (int tp = 2; tp < 4; ++tp) {
            #pragma unroll
            for (int rq = 0; rq < 4; ++rq) {
                const float4v bq = *(const float4v*)&b1_lds[d][32 * tp + 8 * rq + 4 * sh1];
                const float4v wq = *(const float4v*)&w1r_lds[d][32 * tp + 8 * rq + 4 * sh1];
                #pragma unroll
                for (int rr = 0; rr < 4; ++rr)
                    hacc[tp][4 * rq + rr] = fmaf(fe, wq[rr], bq[rr]);
            }
        }
        __builtin_amdgcn_s_setprio(1);
        #pragma unroll
        for (int K = 0; K < 8; ++K) {
            #pragma unroll
            for (int tp = 2; tp < 4; ++tp) {
                const short8 aw = *(const short8*)&su[((tp - 2) * 8 + K) * 512 + lane * 8];
                hacc[tp] = __builtin_amdgcn_mfma_f32_32x32x16_bf16(aw, xf[K].s, hacc[tp], 0, 0, 0);
            }
        }
        __builtin_amdgcn_s_setprio(0);
        pb4();
        ROTATE();

        // ===== P2: stage W1[d+1]h0 -> s2a ; LN ; pack ; GEMM2 tau'0,1 from su ====
        if (d < 3) stage_half(W1T + (d + 1) * 16384, 0, s2a, wv, lane);

        // LN: lane holds 64 ch of ITS edge; partner lane (xor 32) has other 64
        float ps0 = 0.f, ps1 = 0.f, ps2 = 0.f, ps3 = 0.f;
        float pq0 = 0.f, pq1 = 0.f, pq2 = 0.f, pq3 = 0.f;
        #pragma unroll
        for (int tp = 0; tp < 4; ++tp) {
            #pragma unroll
            for (int e = 0; e < 4; ++e) {
                const float v0 = hacc[tp][4 * e + 0];
                const float v1 = hacc[tp][4 * e + 1];
                const float v2 = hacc[tp][4 * e + 2];
                const float v3 = hacc[tp][4 * e + 3];
                ps0 += v0; pq0 = fmaf(v0, v0, pq0);
                ps1 += v1; pq1 = fmaf(v1, v1, pq1);
                ps2 += v2; pq2 = fmaf(v2, v2, pq2);
                ps3 += v3; pq3 = fmaf(v3, v3, pq3);
            }
        }
        float sm = (ps0 + ps1) + (ps2 + ps3);
        float sq = (pq0 + pq1) + (pq2 + pq3);
        sm += __shfl_xor(sm, 32, 64);
        sq += __shfl_xor(sq, 32, 64);
        const float mu   = sm * (1.f / 128.f);
        const float var  = sq * (1.f / 128.f) - mu * mu;
        const float rinv = rsqrtf(var + 1e-5f);
        #pragma unroll
        for (int tp = 0; tp < 4; ++tp) {
            #pragma unroll
            for (int rq = 0; rq < 4; ++rq) {
                const uint4v gb = *(const uint4v*)&gmbt_lds[d][32 * tp + 8 * rq + 4 * sh1];
                #pragma unroll
                for (int rr = 0; rr < 4; ++rr) {
                    const float gv = __uint_as_float(gb[rr] << 16);
                    const float bv = __uint_as_float(gb[rr] & 0xFFFF0000u);
                    float v = (hacc[tp][4 * rq + rr] - mu) * rinv;
                    v = fmaf(v, gv, bv);
                    hacc[tp][4 * rq + rr] = fmaxf(v, 0.f);
                }
            }
        }

        Frag bfr[8];   // zero-shuffle: bfr[K] elem j = hacc[K>>1][8*(K&1)+j]
        #pragma unroll
        for (int K = 0; K < 8; ++K) {
            const int th = K >> 1;
            const int p  = (K & 1) * 8;
            #pragma unroll
            for (int q = 0; q < 4; ++q)
                bfr[K].u[q] = pack2(hacc[th][p + 2 * q], hacc[th][p + 2 * q + 1]);
        }

        __builtin_amdgcn_s_setprio(1);
        #pragma unroll
        for (int K = 0; K < 8; ++K) {
            #pragma unroll
            for (int tp = 0; tp < 2; ++tp) {
                const short8 aw = *(const short8*)&su[(tp * 8 + K) * 512 + lane * 8];
                y[tp] = __builtin_amdgcn_mfma_f32_32x32x16_bf16(aw, bfr[K].s, y[tp], 0, 0, 0);
            }
        }
        __builtin_amdgcn_s_setprio(0);
        if (d < 3) pb4(); else pb0();
        ROTATE();

        // ===== P3: stage W1[d+1]h1 -> s2a ; GEMM2 tau'2,3 from su =====
        if (d < 3) stage_half(W1T + (d + 1) * 16384, 1, s2a, wv, lane);

        __builtin_amdgcn_s_setprio(1);
        #pragma unroll
        for (int K = 0; K < 8; ++K) {
            #pragma unroll
            for (int tp = 2; tp < 4; ++tp) {
                const short8 aw = *(const short8*)&su[((tp - 2) * 8 + K) * 512 + lane * 8];
                y[tp] = __builtin_amdgcn_mfma_f32_32x32x16_bf16(aw, bfr[K].s, y[tp], 0, 0, 0);
            }
        }
        __builtin_amdgcn_s_setprio(0);
        if (d < 3) pb4();
        ROTATE();
    }
    #undef ROTATE

    // ---- store: quads at ch = 32tp + 8rq + 4sh1; 2 lanes cover 32B runs ----
    if (eg < E) {
        #pragma unroll
        for (int tp = 0; tp < 4; ++tp) {
            #pragma unroll
            for (int rq = 0; rq < 4; ++rq) {
                float4v o;
                #pragma unroll
                for (int rr = 0; rr < 4; ++rr) o[rr] = y[tp][4 * rq + rr];
                *(float4v*)(out + eg * 128 + 32 * tp + 8 * rq + 4 * sh1) = o;
            }
        }
    }
}

} // namespace

extern "C" void kernel_launch(void* const* d_in, const int* in_sizes, int n_in,
                              void* d_out, int out_size, void* d_ws, size_t ws_size,
                              hipStream_t stream) {
    const float* source = (const float*)d_in[0];
    const float* target = (const float*)d_in[1];
    const int*   edge   = (const int*)  d_in[2];
    const float* freqs  = (const float*)d_in[3];
    const float* W1     = (const float*)d_in[4];
    const float* b1     = (const float*)d_in[5];
    const float* gammap = (const float*)d_in[6];
    const float* betap  = (const float*)d_in[7];
    const float* W2     = (const float*)d_in[8];
    const float* b2     = (const float*)d_in[9];
    float* out = (float*)d_out;

    ushort* W1T = (ushort*)d_ws;                       // 131072 B
    ushort* W2T = (ushort*)((char*)d_ws + 131072);     // 131072 B

    const int E = in_sizes[2] / 2;      // edge is (2, E); E = 200000

    prep_weights<<<dim3(512), dim3(256), 0, stream>>>(W1, W2, W1T, W2T);

    const int nblocks = (E + 127) / 128;   // 1563 (tail block: 64 edges)
    rcpe_w32<<<dim3(nblocks), dim3(256), 0, stream>>>(
        source, target, edge, freqs, W1, W1T, b1, gammap, betap, W2T, b2, out, E);
}

// Round 14
// 111.798 us; speedup vs baseline: 1.2259x; 1.0421x over previous
//
#include <hip/hip_runtime.h>
#include <hip/hip_bf16.h>
#include <math.h>

namespace {

typedef __attribute__((ext_vector_type(8))) short  short8;
typedef __attribute__((ext_vector_type(4))) float  float4v;

constexpr float PI_F     = 3.14159265358979323846f;
constexpr float TWO_PI_F = 6.28318530717958647692f;

__device__ __forceinline__ unsigned pack2(float a, float b) {
    __hip_bfloat162 h = __float22bfloat162_rn(float2{a, b});
    unsigned r;
    __builtin_memcpy(&r, &h, 4);
    return r;
}

union Frag { unsigned u[4]; short8 s; };

__device__ __forceinline__ void gl2lds16(const void* g, void* l) {
    __builtin_amdgcn_global_load_lds(
        (const __attribute__((address_space(1))) void*)g,
        (__attribute__((address_space(3))) void*)l, 16, 0, 0);
}

// counted phase barrier: vmcnt(2) leaves THIS phase's 2 stage-loads in flight,
// forces the previous phase's stage landed. lgkmcnt(0): our ds reads/writes
// retired before signaling. sched_barrier(0): nothing hoists above the waits.
__device__ __forceinline__ void pb2() {
    asm volatile("s_waitcnt vmcnt(2) lgkmcnt(0)" ::: "memory");
    __builtin_amdgcn_s_barrier();
    __builtin_amdgcn_sched_barrier(0);
}
__device__ __forceinline__ void pb0() {
    asm volatile("s_waitcnt vmcnt(0) lgkmcnt(0)" ::: "memory");
    __builtin_amdgcn_s_barrier();
    __builtin_amdgcn_sched_barrier(0);
}

// ---- prep: transpose + bf16 weights.
// W1T[d][n][k]   = W1[d][k][n]               (k < 128; k=128 handled as f32 rank-1)
// W2T[d][n][ks_] = W2[d][pi(ks_)][n], pi makes GEMM2's B-frag lane-local:
//   pi(kslot) = 32*(kslot>>5) + 16*((kslot>>2)&1) + 4*((kslot>>3)&3) + (kslot&3)
__global__ __launch_bounds__(256)
void prep_weights(const float* __restrict__ W1,
                  const float* __restrict__ W2,
                  ushort* __restrict__ W1T,
                  ushort* __restrict__ W2T) {
    const int idx = blockIdx.x * 256 + threadIdx.x;   // 0 .. 131071
    if (idx < 65536) {
        const int d = idx >> 14;
        const int n = (idx >> 7) & 127;
        const int k = idx & 127;
        __hip_bfloat16 v = __float2bfloat16(W1[(d * 129 + k) * 128 + n]);
        ushort u; __builtin_memcpy(&u, &v, 2);
        W1T[idx] = u;
    } else {
        const int j = idx - 65536;
        const int d = j >> 14;
        const int n = (j >> 7) & 127;
        const int kslot = j & 127;
        const int c = 32 * (kslot >> 5) + 16 * ((kslot >> 2) & 1)
                    + 4 * ((kslot >> 3) & 3) + (kslot & 3);
        __hip_bfloat16 v = __float2bfloat16(W2[(d * 128 + c) * 128 + n]);
        ushort u; __builtin_memcpy(&u, &v, 2);
        W2T[j] = u;
    }
}

// stage one 16KB half-tile (16 x 1KB chunks); wave wv stages chunks 2wv, 2wv+1.
// chunk c = tt*4+ks holds A-frags for channel-tile t = 4*half+tt, kstep ks.
__device__ __forceinline__ void stage_half(const ushort* __restrict__ Wtile,
                                           int half, ushort* slot, int wv, int lane) {
    const int e4 = lane & 15;
    const int g  = lane >> 4;
    #pragma unroll
    for (int i = 0; i < 2; ++i) {
        const int c  = 2 * wv + i;
        const int tt = c >> 2;
        const int ks = c & 3;
        const ushort* gp = Wtile + (16 * (4 * half + tt) + e4) * 128 + g * 8 + 32 * ks;
        gl2lds16(gp, slot + c * 512);
    }
}

// ---- main fused kernel ----
// 8 waves x 16 edges = 128 edges/block. Transposed math: h^T = W1^T x^T.
// 16x16x32 MFMA. A (weights): row = lane&15 (ch%16), kslot = (lane>>4)*8+j+32ks.
// B (x / h): col = lane&15 (edge), same kslot layout.
// C: col = lane&15 (edge), ch = 16t + 4*(lane>>4) + reg.
// 4 phases per d; 3 rotating 16KB slots; stage issued 2 phases ahead of use.
__global__ __launch_bounds__(512, 4)
void rcpe_rot(const float* __restrict__ source,
              const float* __restrict__ target,
              const int*   __restrict__ edge,
              const float* __restrict__ freqs,
              const float* __restrict__ W1,      // f32, for k=128 rank-1 row
              const ushort* __restrict__ W1T,
              const float* __restrict__ b1,
              const float* __restrict__ gamma,
              const float* __restrict__ beta,
              const ushort* __restrict__ W2T,
              const float* __restrict__ b2,
              float* __restrict__ out,
              int E)
{
    __shared__ __align__(16) ushort wbuf[3][8192];    // 3 x 16 KB rotating slots
    __shared__ __align__(16) float b1_lds[4][128];
    __shared__ __align__(16) float gm_lds[4][128];
    __shared__ __align__(16) float bt_lds[4][128];
    __shared__ __align__(16) float w1r_lds[4][128];
    __shared__ __align__(16) float feat_lds[4][128];
    __shared__ __align__(16) float freq_lds[4][64];

    const int tid  = threadIdx.x;     // 0..511
    const int wv   = tid >> 6;        // 0..7
    const int lane = tid & 63;
    const int e4   = lane & 15;
    const int g    = lane >> 4;       // 0..3
    const int ebase = blockIdx.x * 128;
    const int eg    = ebase + wv * 16 + e4;

    // ---- prologue: issue phase-0 and phase-1 stages FIRST (oldest in FIFO) ----
    stage_half(W1T, 0, wbuf[0], wv, lane);   // phase 0 data: W1[0] t0-3
    stage_half(W1T, 1, wbuf[1], wv, lane);   // phase 1 data: W1[0] t4-7
    __builtin_amdgcn_sched_barrier(0);       // pin stage issue before other vmem

    {   // param tables (prologue-only vmem; loop has ONLY stage loads as vmem)
        const int dd = tid >> 7, c = tid & 127;
        b1_lds[dd][c]  = b1[tid];
        gm_lds[dd][c]  = gamma[tid];
        bt_lds[dd][c]  = beta[tid];
        w1r_lds[dd][c] = W1[(dd * 129 + 128) * 128 + c];
    }
    if (tid < 256) ((float*)freq_lds)[tid] = freqs[tid];

    if (tid < 128) {
        const int e  = ebase + tid;
        const int ec = (e < E) ? e : (E - 1);
        const int s_i = edge[ec];
        const int t_i = edge[E + ec];
        const float sx = source[s_i * 3 + 0];
        const float sy = source[s_i * 3 + 1];
        const float sh = source[s_i * 3 + 2];
        const float tx = target[t_i * 5 + 0];
        const float ty = target[t_i * 5 + 1];
        const float th = target[t_i * 5 + 2];
        const float ts = target[t_i * 5 + 3];
        const float dx = sx - tx;
        const float dy = sy - ty;
        float a = sh - th + PI_F;
        a = fmodf(a, TWO_PI_F);
        if (a < 0.0f) a += TWO_PI_F;
        const float dh  = a - PI_F;
        const float ang = atan2f(dy, dx);
        const float tvx = ts * cosf(th);
        const float tvy = ts * sinf(th);
        const float closing = tvx * cosf(ang) + tvy * sinf(ang);
        feat_lds[0][tid] = dx;
        feat_lds[1][tid] = dy;
        feat_lds[2][tid] = dh;
        feat_lds[3][tid] = closing;
    }

    // y init: sum_d b2 (C layout: ch = 16t + 4g + r)
    float4v y[8];
    #pragma unroll
    for (int t = 0; t < 8; ++t) {
        float4v a = {0.f, 0.f, 0.f, 0.f};
        #pragma unroll
        for (int d = 0; d < 4; ++d) {
            const float4v bv = *(const float4v*)(b2 + d * 128 + 16 * t + 4 * g);
            #pragma unroll
            for (int r = 0; r < 4; ++r) a[r] += bv[r];
        }
        y[t] = a;
    }

    pb2();   // params drained by their own dependency waits; slots 0,1 landed

    // rotating slot pointers: su = this phase's data, s1a = next, s2a = stage dst
    ushort* su  = wbuf[0];
    ushort* s1a = wbuf[1];
    ushort* s2a = wbuf[2];
    #define ROTATE() { ushort* _t = su; su = s1a; s1a = s2a; s2a = _t; }

    #pragma unroll 1
    for (int d = 0; d < 4; ++d) {
        const float fe = feat_lds[d][wv * 16 + e4];

        // ===== P0: stage W2[d]h0 -> s2a ; trig ; GEMM1 t0-3 from su =====
        stage_half(W2T + d * 16384, 0, s2a, wv, lane);

        Frag xf[4];   // ks0=cos lo, ks1=cos hi, ks2=sin lo, ks3=sin hi
        {
            float cl[8], sl[8], ch8[8], sh8[8];
            #pragma unroll
            for (int j = 0; j < 8; ++j) {
                const float frL = freq_lds[d][8 * g + j];
                const float frH = freq_lds[d][32 + 8 * g + j];
                const float tL = __builtin_amdgcn_fractf(fe * frL);
                const float tH = __builtin_amdgcn_fractf(fe * frH);
                sl[j]  = __builtin_amdgcn_sinf(tL);
                cl[j]  = __builtin_amdgcn_cosf(tL);
                sh8[j] = __builtin_amdgcn_sinf(tH);
                ch8[j] = __builtin_amdgcn_cosf(tH);
            }
            #pragma unroll
            for (int p = 0; p < 4; ++p) {
                xf[0].u[p] = pack2(cl[2 * p],  cl[2 * p + 1]);
                xf[1].u[p] = pack2(ch8[2 * p], ch8[2 * p + 1]);
                xf[2].u[p] = pack2(sl[2 * p],  sl[2 * p + 1]);
                xf[3].u[p] = pack2(sh8[2 * p], sh8[2 * p + 1]);
            }
        }

        float4v hacc[8];
        __builtin_amdgcn_s_setprio(1);
        #pragma unroll
        for (int t = 0; t < 4; ++t) {
            float4v acc = *(const float4v*)&b1_lds[d][16 * t + 4 * g];
            #pragma unroll
            for (int ks = 0; ks < 4; ++ks) {
                const short8 aw = *(const short8*)&su[(t * 4 + ks) * 512 + lane * 8];
                acc = __builtin_amdgcn_mfma_f32_16x16x32_bf16(aw, xf[ks].s, acc, 0, 0, 0);
            }
            hacc[t] = acc;
        }
        __builtin_amdgcn_s_setprio(0);
        pb2();
        ROTATE();

        // ===== P1: stage W2[d]h1 -> s2a ; GEMM1 t4-7 from su ; rank-1 =====
        stage_half(W2T + d * 16384, 1, s2a, wv, lane);

        __builtin_amdgcn_s_setprio(1);
        #pragma unroll
        for (int t = 4; t < 8; ++t) {
            float4v acc = *(const float4v*)&b1_lds[d][16 * t + 4 * g];
            #pragma unroll
            for (int ks = 0; ks < 4; ++ks) {
                const short8 aw = *(const short8*)&su[((t - 4) * 4 + ks) * 512 + lane * 8];
                acc = __builtin_amdgcn_mfma_f32_16x16x32_bf16(aw, xf[ks].s, acc, 0, 0, 0);
            }
            hacc[t] = acc;
        }
        __builtin_amdgcn_s_setprio(0);

        #pragma unroll
        for (int t = 0; t < 8; ++t) {   // rank-1: k=128 raw-feature column, exact f32
            const float4v wv4 = *(const float4v*)&w1r_lds[d][16 * t + 4 * g];
            #pragma unroll
            for (int r = 0; r < 4; ++r)
                hacc[t][r] = fmaf(fe, wv4[r], hacc[t][r]);
        }
        pb2();
        ROTATE();

        // ===== P2: stage W1[d+1]h0 -> s2a ; LN ; pack ; GEMM2 t0-3 from su =====
        if (d < 3) stage_half(W1T + (d + 1) * 16384, 0, s2a, wv, lane);

        float sm = 0.f, sq = 0.f;
        #pragma unroll
        for (int t = 0; t < 8; ++t) {
            #pragma unroll
            for (int r = 0; r < 4; ++r) {
                const float v = hacc[t][r];
                sm += v;
                sq = fmaf(v, v, sq);
            }
        }
        sm += __shfl_xor(sm, 16, 64);
        sq += __shfl_xor(sq, 16, 64);
        sm += __shfl_xor(sm, 32, 64);
        sq += __shfl_xor(sq, 32, 64);
        const float mu   = sm * (1.f / 128.f);
        const float var  = sq * (1.f / 128.f) - mu * mu;
        const float rinv = rsqrtf(var + 1e-5f);
        #pragma unroll
        for (int t = 0; t < 8; ++t) {
            const float4v gv = *(const float4v*)&gm_lds[d][16 * t + 4 * g];
            const float4v bv = *(const float4v*)&bt_lds[d][16 * t + 4 * g];
            #pragma unroll
            for (int r = 0; r < 4; ++r) {
                float v = (hacc[t][r] - mu) * rinv;
                v = fmaf(v, gv[r], bv[r]);
                hacc[t][r] = fmaxf(v, 0.f);
            }
        }

        Frag bfr[4];   // zero-shuffle B-frags (pi-permuted W2T makes them lane-local)
        #pragma unroll
        for (int ks = 0; ks < 4; ++ks) {
            bfr[ks].u[0] = pack2(hacc[2 * ks][0],     hacc[2 * ks][1]);
            bfr[ks].u[1] = pack2(hacc[2 * ks][2],     hacc[2 * ks][3]);
            bfr[ks].u[2] = pack2(hacc[2 * ks + 1][0], hacc[2 * ks + 1][1]);
            bfr[ks].u[3] = pack2(hacc[2 * ks + 1][2], hacc[2 * ks + 1][3]);
        }

        __builtin_amdgcn_s_setprio(1);
        #pragma unroll
        for (int t = 0; t < 4; ++t) {
            float4v acc = y[t];
            #pragma unroll
            for (int ks = 0; ks < 4; ++ks) {
                const short8 aw = *(const short8*)&su[(t * 4 + ks) * 512 + lane * 8];
                acc = __builtin_amdgcn_mfma_f32_16x16x32_bf16(aw, bfr[ks].s, acc, 0, 0, 0);
            }
            y[t] = acc;
        }
        __builtin_amdgcn_s_setprio(0);
        if (d < 3) pb2(); else pb0();   // no stage issued when d==3 -> counts shift
        ROTATE();

        // ===== P3: stage W1[d+1]h1 -> s2a ; GEMM2 t4-7 from su =====
        if (d < 3) stage_half(W1T + (d + 1) * 16384, 1, s2a, wv, lane);

        __builtin_amdgcn_s_setprio(1);
        #pragma unroll
        for (int t = 4; t < 8; ++t) {
            float4v acc = y[t];
            #pragma unroll
            for (int ks = 0; ks < 4; ++ks) {
                const short8 aw = *(const short8*)&su[((t - 4) * 4 + ks) * 512 + lane * 8];
                acc = __builtin_amdgcn_mfma_f32_16x16x32_bf16(aw, bfr[ks].s, acc, 0, 0, 0);
            }
            y[t] = acc;
        }
        __builtin_amdgcn_s_setprio(0);
        if (d < 3) pb2();
        ROTATE();
    }
    #undef ROTATE

    // ---- store: 4 g-lanes per edge form full 64B sectors ----
    if (eg < E) {
        #pragma unroll
        for (int t = 0; t < 8; ++t) {
            *(float4v*)(out + eg * 128 + 16 * t + 4 * g) = y[t];
        }
    }
}

} // namespace

extern "C" void kernel_launch(void* const* d_in, const int* in_sizes, int n_in,
                              void* d_out, int out_size, void* d_ws, size_t ws_size,
                              hipStream_t stream) {
    const float* source = (const float*)d_in[0];
    const float* target = (const float*)d_in[1];
    const int*   edge   = (const int*)  d_in[2];
    const float* freqs  = (const float*)d_in[3];
    const float* W1     = (const float*)d_in[4];
    const float* b1     = (const float*)d_in[5];
    const float* gammap = (const float*)d_in[6];
    const float* betap  = (const float*)d_in[7];
    const float* W2     = (const float*)d_in[8];
    const float* b2     = (const float*)d_in[9];
    float* out = (float*)d_out;

    ushort* W1T = (ushort*)d_ws;                       // 131072 B
    ushort* W2T = (ushort*)((char*)d_ws + 131072);     // 131072 B

    const int E = in_sizes[2] / 2;      // edge is (2, E); E = 200000

    prep_weights<<<dim3(512), dim3(256), 0, stream>>>(W1, W2, W1T, W2T);

    const int nblocks = (E + 127) / 128;   // 1563 (tail block: 64 edges)
    rcpe_rot<<<dim3(nblocks), dim3(512), 0, stream>>>(
        source, target, edge, freqs, W1, W1T, b1, gammap, betap, W2T, b2, out, E);
}